// Round 2
// baseline (502.273 us; speedup 1.0000x reference)
//
#include <hip/hip_runtime.h>
#include <cstdint>
#include <cstddef>

#define NNODES 50000
#define TT 24
#define DYNF 16
#define STATF 8
#define HDIM 64
#define NEDGES 1600000
#define GRUB 782       // GRU blocks: 64 nodes/block (4 waves x 16 nodes)
#define FILL_CHUNK 1024
#define FILL_CHUNKS ((NEDGES + FILL_CHUNK - 1) / FILL_CHUNK)  // 1563
#define CAP 80         // bucket capacity per node (deg~Poisson(32), max~57)

typedef __attribute__((ext_vector_type(8))) short bf16x8;
typedef __attribute__((ext_vector_type(4))) float f32x4;
typedef __attribute__((ext_vector_type(2))) float f32x2;
typedef __attribute__((ext_vector_type(2))) unsigned u32x2;

// fp32 -> bf16 with round-to-nearest-even
__device__ __forceinline__ unsigned short f2bf(float f) {
    unsigned u = __float_as_uint(f);
    u = (u + 0x7FFFu + ((u >> 16) & 1u)) >> 16;
    return (unsigned short)u;
}
__device__ __forceinline__ float bf2f(unsigned short s) {
    return __uint_as_float((unsigned)s << 16);
}
__device__ __forceinline__ bf16x8 cvt8(const float* __restrict__ p) {
    bf16x8 r;
    #pragma unroll
    for (int i = 0; i < 8; ++i) r[i] = (short)f2bf(p[i]);
    return r;
}
__device__ __forceinline__ bf16x8 zero8() {
    bf16x8 z;
    #pragma unroll
    for (int i = 0; i < 8; ++i) z[i] = 0;
    return z;
}
// robust fast tanh: no inf/inf NaN at extremes
__device__ __forceinline__ float fast_tanh(float x) {
    float e = __expf(2.f * x);
    return 1.f - 2.f * __builtin_amdgcn_rcpf(e + 1.f);
}

// ---------------------------------------------------------------------------
// Heterogeneous launch: blocks [0, GRUB) = barrier-free GRU + fused W1;
// blocks beyond = bucket-CSR fill (XCD dst-range partitioned).
//
// GRU restructure (this round): operand-swapped MFMA (gh^T = Whh * h^T).
// Weights are the A-operand (row = gate), state is the B-operand (col =
// node). One wave owns 16 nodes end-to-end -> the h recurrence never
// crosses waves: NO __syncthreads in the 24-step loop. h roundtrips
// through a 2KB wave-local LDS scratch (same-wave DS ops are in-order),
// XOR-swizzled to stay ~2-way bank-conflict-free.
// Biases b_r,b_z,b_xn are folded into a constant-1.0 slot of the x-ktile
// (K=32, DYNF=16 -> k=16 slot carries the bias column); b_hn stays in regs.
// ---------------------------------------------------------------------------
__global__ __launch_bounds__(256, 2) void gru_fill_kernel(
    const float* __restrict__ x_dyn, const float* __restrict__ x_stat,
    const float* __restrict__ Wih, const float* __restrict__ Whh,
    const float* __restrict__ bih, const float* __restrict__ bhh,
    const float* __restrict__ W1, unsigned short* __restrict__ t1,
    const int* __restrict__ srcv, const int* __restrict__ dstv,
    const float* __restrict__ ew, int* __restrict__ cursor,
    unsigned* __restrict__ csr)
{
    __shared__ short hsc[4][1024];   // per-wave 16 nodes x 64 bf16 (swizzled)

    const int tid = (int)threadIdx.x;

    if ((int)blockIdx.x >= GRUB) {
        // ---------------- bucket-CSR fill ----------------
        const int fb = (int)blockIdx.x - GRUB;
        const int range = fb & 7;                  // XCD round-robin slice
        const int chunk = fb >> 3;
        const int base = chunk * FILL_CHUNK;
        const int lo = range * (NNODES / 8);
        const int hi = (range == 7) ? NNODES : lo + (NNODES / 8);
        #pragma unroll
        for (int j = 0; j < FILL_CHUNK / 256; ++j) {
            const int e = base + j * 256 + tid;
            if (e < NEDGES) {
                const int d = dstv[e];
                if (d >= lo && d < hi) {
                    const int s = __builtin_nontemporal_load(srcv + e);
                    const float we = __builtin_nontemporal_load(ew + e);
                    const int pos = atomicAdd(&cursor[d], 1);
                    if (pos < CAP)
                        csr[(size_t)d * CAP + pos] =
                            (unsigned)s | ((unsigned)f2bf(we) << 16);
                }
            }
        }
        return;
    }

    // ---------------- barrier-free GRU + W1 ----------------
    const int lane = tid & 63;
    const int wv = tid >> 6;          // wave 0..3, fully independent
    const int col = lane & 15;        // node within wave tile
    const int quad = lane >> 4;

    int node0 = (int)blockIdx.x * 64 + wv * 16;
    const bool active = node0 < NNODES;   // wave-uniform (50000 % 16 == 0)
    if (!active) node0 = 0;

    // ---- weight fragments (A-operand: row = gate feature, k = quad*8+j) ----
    bf16x8 Wh[3][4][2];   // [gate r/z/n][feature tile][k-tile]
    bf16x8 Wx[3][4];      // x-ktile (k=0..15 real, k=16 bias column)
    #pragma unroll
    for (int g = 0; g < 3; ++g) {
        #pragma unroll
        for (int ft = 0; ft < 4; ++ft) {
            const int row = g * 64 + ft * 16 + col;   // gate row in [0,192)
            Wh[g][ft][0] = cvt8(Whh + (size_t)row * HDIM + quad * 8);
            Wh[g][ft][1] = cvt8(Whh + (size_t)row * HDIM + 32 + quad * 8);
            if (quad < 2) {
                Wx[g][ft] = cvt8(Wih + (size_t)row * DYNF + quad * 8);
            } else {
                bf16x8 z = zero8();
                if (quad == 2) {   // k=16: bias column (multiplied by 1.0)
                    const float bias = bih[row] + ((g < 2) ? bhh[row] : 0.f);
                    z[0] = (short)f2bf(bias);
                }
                Wx[g][ft] = z;
            }
        }
    }
    float bhn[4][4];   // b_hn: must multiply by r-gate -> stays separate
    #pragma unroll
    for (int ft = 0; ft < 4; ++ft)
        #pragma unroll
        for (int r = 0; r < 4; ++r)
            bhn[ft][r] = bhh[128 + ft * 16 + quad * 4 + r];

    // ---- wave-local LDS scratch (XOR-swizzled, ~2-way conflicts) ----
    short* hs = &hsc[wv][0];
    const int wsw = (col & 7) << 3;   // swizzle in short units (16B blocks)

    // ---- x loader: B-frag x_aug[node][k], quad0/1 real, quad2 j0 = 1.0 ----
    auto xload = [&](int t, f32x4& lo, f32x4& hi) {
        if (quad < 2) {
            const float* p = x_dyn + (size_t)(node0 + col) * (TT * DYNF)
                           + t * DYNF + quad * 8;
            lo = *reinterpret_cast<const f32x4*>(p);
            hi = *reinterpret_cast<const f32x4*>(p + 4);
        }
    };
    auto xcvt = [&](f32x4 lo, f32x4 hi) -> bf16x8 {
        bf16x8 b;
        if (quad < 2) {
            #pragma unroll
            for (int i = 0; i < 4; ++i) {
                b[i] = (short)f2bf(lo[i]);
                b[4 + i] = (short)f2bf(hi[i]);
            }
        } else {
            b = zero8();
            if (quad == 2) b[0] = (short)0x3F80;   // bf16(1.0) bias slot
        }
        return b;
    };

    f32x4 xlo, xhi;
    xload(0, xlo, xhi);
    bf16x8 Bh0 = zero8(), Bh1 = zero8();   // h0 = 0
    bf16x8 Bx = xcvt(xlo, xhi);

    float hprev[4][4];
    #pragma unroll
    for (int ft = 0; ft < 4; ++ft)
        #pragma unroll
        for (int r = 0; r < 4; ++r) hprev[ft][r] = 0.f;

    const f32x4 z4 = {0.f, 0.f, 0.f, 0.f};

    for (int t = 0; t < TT; ++t) {
        f32x4 nlo, nhi;
        if (t + 1 < TT) xload(t + 1, nlo, nhi);   // prefetch under MFMAs

        #pragma unroll
        for (int ft = 0; ft < 4; ++ft) {
            f32x4 ar, az, anh, anx;
            ar  = __builtin_amdgcn_mfma_f32_16x16x32_bf16(Wh[0][ft][0], Bh0, z4, 0, 0, 0);
            ar  = __builtin_amdgcn_mfma_f32_16x16x32_bf16(Wh[0][ft][1], Bh1, ar, 0, 0, 0);
            ar  = __builtin_amdgcn_mfma_f32_16x16x32_bf16(Wx[0][ft],    Bx,  ar, 0, 0, 0);
            az  = __builtin_amdgcn_mfma_f32_16x16x32_bf16(Wh[1][ft][0], Bh0, z4, 0, 0, 0);
            az  = __builtin_amdgcn_mfma_f32_16x16x32_bf16(Wh[1][ft][1], Bh1, az, 0, 0, 0);
            az  = __builtin_amdgcn_mfma_f32_16x16x32_bf16(Wx[1][ft],    Bx,  az, 0, 0, 0);
            anh = __builtin_amdgcn_mfma_f32_16x16x32_bf16(Wh[2][ft][0], Bh0, z4, 0, 0, 0);
            anh = __builtin_amdgcn_mfma_f32_16x16x32_bf16(Wh[2][ft][1], Bh1, anh, 0, 0, 0);
            anx = __builtin_amdgcn_mfma_f32_16x16x32_bf16(Wx[2][ft],    Bx,  z4, 0, 0, 0);

            unsigned plo, phi;
            #pragma unroll
            for (int r = 0; r < 4; ++r) {
                const float dr = 1.f + __expf(-ar[r]);
                const float dz = 1.f + __expf(-az[r]);
                const float q  = __builtin_amdgcn_rcpf(dr * dz);
                const float R  = q * dz;           // = 1/dr
                const float Z  = q * dr;           // = 1/dz
                const float Nn = fast_tanh(anx[r] + R * (anh[r] + bhn[ft][r]));
                const float hn = Nn + Z * (hprev[ft][r] - Nn);
                hprev[ft][r] = hn;
                const unsigned hb = f2bf(hn);
                if (r == 0) plo = hb;
                else if (r == 1) plo |= hb << 16;
                else if (r == 2) phi = hb;
                else phi |= hb << 16;
            }
            // C layout: h[node=col][f = ft*16 + quad*4 + r] -> swizzled write
            u32x2 pk; pk[0] = plo; pk[1] = phi;
            *reinterpret_cast<u32x2*>(
                &hs[col * 64 + ((ft * 16 + quad * 4) ^ wsw)]) = pk;
        }

        // next-step B-frag: h[node=col][k = kt*32 + quad*8 + j] (same-wave
        // DS ordering guarantees the 4 writes above land first)
        Bh0 = *reinterpret_cast<const bf16x8*>(&hs[col * 64 + ((quad * 8) ^ wsw)]);
        Bh1 = *reinterpret_cast<const bf16x8*>(&hs[col * 64 + ((32 + quad * 8) ^ wsw)]);
        if (t + 1 < TT) Bx = xcvt(nlo, nhi);
    }

    if (!active) return;

    // ---- fused W1: t1^T = W1^T * [h | x_stat]^T (bf16 out) ----
    bf16x8 Aw[4][2];   // [out tile][k-tile] : W1[k][o], strided loads
    #pragma unroll
    for (int ot = 0; ot < 4; ++ot)
        #pragma unroll
        for (int kt = 0; kt < 2; ++kt)
            #pragma unroll
            for (int j = 0; j < 8; ++j)
                Aw[ot][kt][j] = (short)f2bf(
                    W1[(size_t)(kt * 32 + quad * 8 + j) * HDIM + ot * 16 + col]);
    bf16x8 Aw2[4];
    #pragma unroll
    for (int ot = 0; ot < 4; ++ot) {
        if (quad == 0) {
            #pragma unroll
            for (int j = 0; j < 8; ++j)
                Aw2[ot][j] = (short)f2bf(
                    W1[(size_t)(HDIM + j) * HDIM + ot * 16 + col]);
        } else {
            Aw2[ot] = zero8();
        }
    }
    bf16x8 Bxs;
    if (quad == 0) Bxs = cvt8(x_stat + (size_t)(node0 + col) * STATF);
    else Bxs = zero8();

    #pragma unroll
    for (int ot = 0; ot < 4; ++ot) {
        f32x4 aw;
        aw = __builtin_amdgcn_mfma_f32_16x16x32_bf16(Aw[ot][0], Bh0, z4, 0, 0, 0);
        aw = __builtin_amdgcn_mfma_f32_16x16x32_bf16(Aw[ot][1], Bh1, aw, 0, 0, 0);
        aw = __builtin_amdgcn_mfma_f32_16x16x32_bf16(Aw2[ot],   Bxs, aw, 0, 0, 0);
        // C: t1[node=col][o = ot*16 + quad*4 + r] -> one 8B store
        u32x2 pk;
        pk[0] = (unsigned)f2bf(aw[0]) | ((unsigned)f2bf(aw[1]) << 16);
        pk[1] = (unsigned)f2bf(aw[2]) | ((unsigned)f2bf(aw[3]) << 16);
        *reinterpret_cast<u32x2*>(
            &t1[(size_t)(node0 + col) * HDIM + ot * 16 + quad * 4]) = pk;
    }
}

// ---------------------------------------------------------------------------
// Layer 1 fused: gather-reduce (bucket CSR) into LDS, then relu(+b1) @ W2
// via MFMA, bf16 out. 16 nodes/block (50000 = 3125*16 exactly).
// ---------------------------------------------------------------------------
__global__ __launch_bounds__(256) void gather_transform_kernel(
    const unsigned short* __restrict__ tsrc, const int* __restrict__ cursor,
    const unsigned* __restrict__ csr, const float* __restrict__ b1,
    const float* __restrict__ W2, unsigned short* __restrict__ out)
{
    __shared__ float aggL[16][68];     // stride 68: 2-way-max bank aliasing
    const int tid  = (int)threadIdx.x;
    const int lane = tid & 63;
    const int w    = tid >> 6;         // wave 0..3
    const int half = lane >> 5;
    const int fl   = lane & 31;        // feature pair (2*fl, 2*fl+1)
    const int col  = lane & 15;
    const int quad = lane >> 4;
    const int node0 = (int)blockIdx.x * 16;
    const int jg = w * 16 + col;

    // preload W2 fragments + bias (latency hides under the gather phase)
    bf16x8 Bw0, Bw1;
    float bk0[8], bk1[8];
    #pragma unroll
    for (int j = 0; j < 8; ++j) {
        Bw0[j] = (short)f2bf(W2[(size_t)(quad * 8 + j) * HDIM + jg]);
        Bw1[j] = (short)f2bf(W2[(size_t)(32 + quad * 8 + j) * HDIM + jg]);
        bk0[j] = b1[quad * 8 + j];
        bk1[j] = b1[32 + quad * 8 + j];
    }

    for (int i = 0; i < 4; ++i) {
        const int nloc = w * 4 + i;
        const int node = node0 + nloc;
        const int beg = node * CAP;
        const int cnt = min(cursor[node], CAP);
        const int end = beg + cnt;
        float ax = 0.f, ay = 0.f;
        int p = beg;
        for (; p + 8 <= end; p += 8) {     // 4 row-requests in flight per half
            unsigned pp[4], pk[4];
            #pragma unroll
            for (int k = 0; k < 4; ++k) pp[k] = csr[p + 2 * k + half];
            #pragma unroll
            for (int k = 0; k < 4; ++k)
                pk[k] = *reinterpret_cast<const unsigned*>(
                    tsrc + (size_t)(pp[k] & 0xFFFFu) * HDIM + 2 * fl);
            #pragma unroll
            for (int k = 0; k < 4; ++k) {
                const float wgt = __uint_as_float(pp[k] & 0xFFFF0000u);
                ax += wgt * bf2f((unsigned short)(pk[k] & 0xFFFFu));
                ay += wgt * bf2f((unsigned short)(pk[k] >> 16));
            }
        }
        for (; p + 2 <= end; p += 2) {
            const unsigned pp = csr[p + half];
            const unsigned pk = *reinterpret_cast<const unsigned*>(
                tsrc + (size_t)(pp & 0xFFFFu) * HDIM + 2 * fl);
            const float wgt = __uint_as_float(pp & 0xFFFF0000u);
            ax += wgt * bf2f((unsigned short)(pk & 0xFFFFu));
            ay += wgt * bf2f((unsigned short)(pk >> 16));
        }
        if (p < end) {                     // single leftover: half 0 contributes
            const unsigned pp = csr[p];
            const unsigned pk = *reinterpret_cast<const unsigned*>(
                tsrc + (size_t)(pp & 0xFFFFu) * HDIM + 2 * fl);
            const float wgt = (half == 0) ? __uint_as_float(pp & 0xFFFF0000u) : 0.f;
            ax += wgt * bf2f((unsigned short)(pk & 0xFFFFu));
            ay += wgt * bf2f((unsigned short)(pk >> 16));
        }
        ax += __shfl_xor(ax, 32, 64);      // combine halves
        ay += __shfl_xor(ay, 32, 64);
        if (half == 0) {
            f32x2 o; o[0] = ax; o[1] = ay;
            *reinterpret_cast<f32x2*>(&aggL[nloc][2 * fl]) = o;
        }
    }
    __syncthreads();

    // ---- transform: t2 = relu(aggL + b1) @ W2 ----
    bf16x8 a0, a1;
    #pragma unroll
    for (int j = 0; j < 8; ++j) {
        a0[j] = (short)f2bf(fmaxf(aggL[col][quad * 8 + j] + bk0[j], 0.f));
        a1[j] = (short)f2bf(fmaxf(aggL[col][32 + quad * 8 + j] + bk1[j], 0.f));
    }
    const f32x4 z4 = {0.f, 0.f, 0.f, 0.f};
    f32x4 aw;
    aw = __builtin_amdgcn_mfma_f32_16x16x32_bf16(a0, Bw0, z4, 0, 0, 0);
    aw = __builtin_amdgcn_mfma_f32_16x16x32_bf16(a1, Bw1, aw, 0, 0, 0);
    #pragma unroll
    for (int r = 0; r < 4; ++r)
        out[(size_t)(node0 + quad * 4 + r) * HDIM + jg] = f2bf(aw[r]);
}

// ---------------------------------------------------------------------------
// Gather + fused head for layer 2 (bucket CSR).
// ---------------------------------------------------------------------------
__global__ __launch_bounds__(256) void gather_head_kernel(
    const unsigned short* __restrict__ tsrc, const int* __restrict__ cursor,
    const unsigned* __restrict__ csr,
    const float* __restrict__ b2, const float* __restrict__ Wa,
    const float* __restrict__ ba, const float* __restrict__ Wp,
    const float* __restrict__ bp, float* __restrict__ out)
{
    const int node = blockIdx.x * 4 + (threadIdx.x >> 6);
    const int lane = (int)threadIdx.x & 63;
    const int half = lane >> 5;
    const int fl = lane & 31;
    if (node >= NNODES) return;
    const int beg = node * CAP;
    const int cnt = min(cursor[node], CAP);
    const int end = beg + cnt;
    float ax = 0.f, ay = 0.f;
    int i = beg;
    for (; i + 8 <= end; i += 8) {
        unsigned p[4], pk[4];
        #pragma unroll
        for (int k = 0; k < 4; ++k) p[k] = csr[i + 2 * k + half];
        #pragma unroll
        for (int k = 0; k < 4; ++k)
            pk[k] = *reinterpret_cast<const unsigned*>(
                tsrc + (size_t)(p[k] & 0xFFFFu) * HDIM + 2 * fl);
        #pragma unroll
        for (int k = 0; k < 4; ++k) {
            const float wgt = __uint_as_float(p[k] & 0xFFFF0000u);
            ax += wgt * bf2f((unsigned short)(pk[k] & 0xFFFFu));
            ay += wgt * bf2f((unsigned short)(pk[k] >> 16));
        }
    }
    for (; i + 2 <= end; i += 2) {
        const unsigned p = csr[i + half];
        const unsigned pk = *reinterpret_cast<const unsigned*>(
            tsrc + (size_t)(p & 0xFFFFu) * HDIM + 2 * fl);
        const float wgt = __uint_as_float(p & 0xFFFF0000u);
        ax += wgt * bf2f((unsigned short)(pk & 0xFFFFu));
        ay += wgt * bf2f((unsigned short)(pk >> 16));
    }
    if (i < end) {
        const unsigned p = csr[i];
        const unsigned pk = *reinterpret_cast<const unsigned*>(
            tsrc + (size_t)(p & 0xFFFFu) * HDIM + 2 * fl);
        const float wgt = (half == 0) ? __uint_as_float(p & 0xFFFF0000u) : 0.f;
        ax += wgt * bf2f((unsigned short)(pk & 0xFFFFu));
        ay += wgt * bf2f((unsigned short)(pk >> 16));
    }
    ax += __shfl_xor(ax, 32, 64);      // every lane now has its feature pair
    ay += __shfl_xor(ay, 32, 64);

    const float2 bb = *reinterpret_cast<const float2*>(b2 + 2 * fl);
    const float2 wa = *reinterpret_cast<const float2*>(Wa + 2 * fl);
    const float2 wp = *reinterpret_cast<const float2*>(Wp + 2 * fl);
    const float h0 = fmaxf(ax + bb.x, 0.f);
    const float h1 = fmaxf(ay + bb.y, 0.f);
    float sa = h0 * wa.x + h1 * wa.y;
    float sp = h0 * wp.x + h1 * wp.y;
    #pragma unroll
    for (int off = 1; off < 32; off <<= 1) {
        sa += __shfl_xor(sa, off, 64);
        sp += __shfl_xor(sp, off, 64);
    }
    if (lane == 0) {
        out[node] = sa + ba[0];
        out[NNODES + node] = sp + bp[0];
    }
}

extern "C" void kernel_launch(void* const* d_in, const int* in_sizes, int n_in,
                              void* d_out, int out_size, void* d_ws, size_t ws_size,
                              hipStream_t stream)
{
    const float* x_dyn  = (const float*)d_in[0];
    const float* x_stat = (const float*)d_in[1];
    const int*   eidx   = (const int*)  d_in[2];
    const float* ew     = (const float*)d_in[3];
    const float* Wih    = (const float*)d_in[4];
    const float* Whh    = (const float*)d_in[5];
    const float* bih    = (const float*)d_in[6];
    const float* bhh    = (const float*)d_in[7];
    const float* W1     = (const float*)d_in[8];
    const float* b1     = (const float*)d_in[9];
    const float* W2     = (const float*)d_in[10];
    const float* b2     = (const float*)d_in[11];
    const float* Wa     = (const float*)d_in[12];
    const float* ba     = (const float*)d_in[13];
    const float* Wp     = (const float*)d_in[14];
    const float* bp     = (const float*)d_in[15];

    const int* srcv = eidx;
    const int* dstv = eidx + NEDGES;

    // workspace layout (4B units)
    const size_t NH = (size_t)NNODES * HDIM;    // 3.2M elements
    float* ws   = (float*)d_ws;
    unsigned short* t1 = (unsigned short*)ws;                 // [NH] bf16
    unsigned short* t2 = (unsigned short*)(ws + NH / 2);      // [NH] bf16
    unsigned* csr = (unsigned*)(ws + NH);             // [NNODES*CAP] packed
    int* cursor = (int*)(csr + (size_t)NNODES * CAP); // [NNODES]

    dim3 blk(256);

    // cursor must be zero before the combined launch
    hipMemsetAsync(cursor, 0, (size_t)NNODES * sizeof(int), stream);

    // ---- GRU + W1 co-scheduled with bucket-CSR fill ----
    gru_fill_kernel<<<dim3(GRUB + FILL_CHUNKS * 8), blk, 0, stream>>>(
        x_dyn, x_stat, Wih, Whh, bih, bhh, W1, t1,
        srcv, dstv, ew, cursor, csr);

    // ---- layer 1 (transform fused into gather) ----
    gather_transform_kernel<<<dim3(NNODES / 16), blk, 0, stream>>>(
        t1, cursor, csr, b1, W2, t2);

    // ---- layer 2 (head fused into gather) ----
    gather_head_kernel<<<dim3((NNODES + 3) / 4), blk, 0, stream>>>(
        t2, cursor, csr, b2, Wa, ba, Wp, bp, (float*)d_out);
}

// Round 3
// 378.870 us; speedup vs baseline: 1.3257x; 1.3257x over previous
//
#include <hip/hip_runtime.h>
#include <cstdint>
#include <cstddef>

#define NNODES 50000
#define TT 24
#define DYNF 16
#define STATF 8
#define HDIM 64
#define NEDGES 1600000
#define NB 32          // nodes per GRU block (16 regressed: VGPR cap -> spill)
#define GRU_BLOCKS ((NNODES + NB - 1) / NB)        // 1563
#define FILL_CHUNK 1024
#define FILL_CHUNKS ((NEDGES + FILL_CHUNK - 1) / FILL_CHUNK)  // 1563
#define CAP 80         // bucket capacity per node (deg~Poisson(32), max~57)

typedef __attribute__((ext_vector_type(8))) short bf16x8;
typedef __attribute__((ext_vector_type(4))) float f32x4;
typedef __attribute__((ext_vector_type(2))) float f32x2;
typedef __attribute__((ext_vector_type(2))) unsigned u32x2;

// fp32 -> bf16 with round-to-nearest-even
__device__ __forceinline__ unsigned short f2bf(float f) {
    unsigned u = __float_as_uint(f);
    u = (u + 0x7FFFu + ((u >> 16) & 1u)) >> 16;
    return (unsigned short)u;
}
__device__ __forceinline__ float bf2f(unsigned short s) {
    return __uint_as_float((unsigned)s << 16);
}
__device__ __forceinline__ bf16x8 cvt8(const float* __restrict__ p) {
    bf16x8 r;
    #pragma unroll
    for (int i = 0; i < 8; ++i) r[i] = (short)f2bf(p[i]);
    return r;
}
__device__ __forceinline__ bf16x8 zero8() {
    bf16x8 z;
    #pragma unroll
    for (int i = 0; i < 8; ++i) z[i] = 0;
    return z;
}
// robust fast tanh: no inf/inf NaN at extremes
__device__ __forceinline__ float fast_tanh(float x) {
    float e = __expf(2.f * x);
    return 1.f - 2.f * __builtin_amdgcn_rcpf(e + 1.f);
}

// ---------------------------------------------------------------------------
// Heterogeneous launch: blocks [0, GRU_BLOCKS) = MFMA GRU + fused W1
// (round-1 verified body, reverted verbatim after the round-2 spill
// regression); blocks beyond = bucket-CSR fill (XCD dst-range partitioned).
// ---------------------------------------------------------------------------
__global__ __launch_bounds__(256, 4) void gru_fill_kernel(
    const float* __restrict__ x_dyn, const float* __restrict__ x_stat,
    const float* __restrict__ Wih, const float* __restrict__ Whh,
    const float* __restrict__ bih, const float* __restrict__ bhh,
    const float* __restrict__ W1, unsigned short* __restrict__ t1,
    const int* __restrict__ srcv, const int* __restrict__ dstv,
    const float* __restrict__ ew, int* __restrict__ cursor,
    unsigned* __restrict__ csr)
{
    constexpr int S_H = 72;   // bf16 units per hbuf row (144B: 16B-aligned)
    constexpr int S_X = 40;   // bf16 units per xbuf row
    __shared__ short hbuf[2][NB * S_H];   // [node][feature] bf16, dbuf
    __shared__ short xbuf[2][NB * S_X];   // [node][k] bf16; k 16..31 zeroed

    const int tid = (int)threadIdx.x;

    if ((int)blockIdx.x >= GRU_BLOCKS) {
        // ---------------- bucket-CSR fill ----------------
        const int fb = (int)blockIdx.x - GRU_BLOCKS;
        const int range = fb & 7;                  // XCD round-robin slice
        const int chunk = fb >> 3;
        const int base = chunk * FILL_CHUNK;
        const int lo = range * (NNODES / 8);
        const int hi = (range == 7) ? NNODES : lo + (NNODES / 8);
        #pragma unroll
        for (int j = 0; j < FILL_CHUNK / 256; ++j) {
            const int e = base + j * 256 + tid;
            if (e < NEDGES) {
                const int d = dstv[e];
                if (d >= lo && d < hi) {
                    const int s = __builtin_nontemporal_load(srcv + e);
                    const float we = __builtin_nontemporal_load(ew + e);
                    const int pos = atomicAdd(&cursor[d], 1);
                    if (pos < CAP)
                        csr[(size_t)d * CAP + pos] =
                            (unsigned)s | ((unsigned)f2bf(we) << 16);
                }
            }
        }
        return;
    }

    // ---------------- GRU + W1 ----------------
    const int lane = tid & 63;
    const int w = __builtin_amdgcn_readfirstlane(tid >> 6);  // wave 0..3
    const int col = lane & 15;
    const int quad = lane >> 4;
    const int node0 = (int)blockIdx.x * NB;

    bf16x8 Bh[3][2];
    bf16x8 Bx[3];
    #pragma unroll
    for (int g = 0; g < 3; ++g) {
        const int n = (w + g * 4) * 16 + col;   // gate row in [0,192)
        #pragma unroll
        for (int kt = 0; kt < 2; ++kt)
            Bh[g][kt] = cvt8(Whh + (size_t)n * HDIM + kt * 32 + quad * 8);
        Bx[g] = (quad < 2) ? cvt8(Wih + (size_t)n * DYNF + quad * 8) : zero8();
    }

    const int jg = w * 16 + col;                 // feature 0..63
    const float b_r  = bih[jg]        + bhh[jg];
    const float b_z  = bih[HDIM + jg] + bhh[HDIM + jg];
    const float b_xn = bih[2 * HDIM + jg];
    const float b_hn = bhh[2 * HDIM + jg];

    for (int i = tid; i < NB * S_H; i += 256) hbuf[0][i] = 0;

    auto stage_x = [&](int t, int b) {
        const int nd = tid >> 3, c = tid & 7;
        int node = node0 + nd;
        if (node >= NNODES) node = 0;
        const f32x2 v = __builtin_nontemporal_load(
            reinterpret_cast<const f32x2*>(
                x_dyn + (size_t)node * (TT * DYNF) + t * DYNF + c * 2));
        unsigned pk = (unsigned)f2bf(v[0]) | ((unsigned)f2bf(v[1]) << 16);
        *reinterpret_cast<unsigned*>(&xbuf[b][nd * S_X + c * 2]) = pk;
        *reinterpret_cast<unsigned*>(&xbuf[b][nd * S_X + 16 + c * 2]) = 0u;
    };
    stage_x(0, 0);

    float hprev[2][4];
    #pragma unroll
    for (int mt = 0; mt < 2; ++mt)
        #pragma unroll
        for (int r = 0; r < 4; ++r) hprev[mt][r] = 0.f;

    for (int t = 0; t < TT; ++t) {
        const int rb = t & 1;
        __syncthreads();   // hbuf[rb], xbuf[rb] ready

        f32x4 accr[2], accz[2], accnh[2], accnx[2];
        #pragma unroll
        for (int mt = 0; mt < 2; ++mt) {
            const int nd = mt * 16 + col;   // A-frag: m = lane&15 within tile
            const bf16x8 a0 = *reinterpret_cast<const bf16x8*>(&hbuf[rb][nd * S_H + quad * 8]);
            const bf16x8 a1 = *reinterpret_cast<const bf16x8*>(&hbuf[rb][nd * S_H + 32 + quad * 8]);
            const bf16x8 ax = *reinterpret_cast<const bf16x8*>(&xbuf[rb][nd * S_X + quad * 8]);
            const f32x4 z4 = {0.f, 0.f, 0.f, 0.f};
            accr[mt]  = __builtin_amdgcn_mfma_f32_16x16x32_bf16(a0, Bh[0][0], z4, 0, 0, 0);
            accr[mt]  = __builtin_amdgcn_mfma_f32_16x16x32_bf16(a1, Bh[0][1], accr[mt], 0, 0, 0);
            accr[mt]  = __builtin_amdgcn_mfma_f32_16x16x32_bf16(ax, Bx[0],    accr[mt], 0, 0, 0);
            accz[mt]  = __builtin_amdgcn_mfma_f32_16x16x32_bf16(a0, Bh[1][0], z4, 0, 0, 0);
            accz[mt]  = __builtin_amdgcn_mfma_f32_16x16x32_bf16(a1, Bh[1][1], accz[mt], 0, 0, 0);
            accz[mt]  = __builtin_amdgcn_mfma_f32_16x16x32_bf16(ax, Bx[1],    accz[mt], 0, 0, 0);
            accnh[mt] = __builtin_amdgcn_mfma_f32_16x16x32_bf16(a0, Bh[2][0], z4, 0, 0, 0);
            accnh[mt] = __builtin_amdgcn_mfma_f32_16x16x32_bf16(a1, Bh[2][1], accnh[mt], 0, 0, 0);
            accnx[mt] = __builtin_amdgcn_mfma_f32_16x16x32_bf16(ax, Bx[2],    z4, 0, 0, 0);
        }

        if (t + 1 < TT) stage_x(t + 1, rb ^ 1);  // overlap with MFMA drain

        #pragma unroll
        for (int mt = 0; mt < 2; ++mt) {
            #pragma unroll
            for (int r = 0; r < 4; ++r) {
                const float dr = 1.f + __expf(-(accr[mt][r] + b_r));
                const float dz = 1.f + __expf(-(accz[mt][r] + b_z));
                const float q  = __builtin_amdgcn_rcpf(dr * dz);
                const float R  = q * dz;           // = 1/dr
                const float Z  = q * dr;           // = 1/dz
                const float Nn = fast_tanh(accnx[mt][r] + b_xn + R * (accnh[mt][r] + b_hn));
                const float hn = Nn + Z * (hprev[mt][r] - Nn);
                hprev[mt][r] = hn;
                hbuf[rb ^ 1][(mt * 16 + quad * 4 + r) * S_H + jg] = (short)f2bf(hn);
            }
        }
    }
    __syncthreads();   // final h in hbuf[0]

    // ---- fused W1: t1 = [h | x_stat] @ W1 (bf16 out) ----
    bf16x8 Bw0, Bw1, Bw2;
    #pragma unroll
    for (int j = 0; j < 8; ++j) {
        Bw0[j] = (short)f2bf(W1[(size_t)(quad * 8 + j) * HDIM + jg]);
        Bw1[j] = (short)f2bf(W1[(size_t)(32 + quad * 8 + j) * HDIM + jg]);
    }
    if (quad == 0) {
        #pragma unroll
        for (int j = 0; j < 8; ++j)
            Bw2[j] = (short)f2bf(W1[(size_t)(HDIM + j) * HDIM + jg]);
    } else {
        Bw2 = zero8();
    }

    #pragma unroll
    for (int mt = 0; mt < 2; ++mt) {
        const int nd = mt * 16 + col;
        const bf16x8 a0 = *reinterpret_cast<const bf16x8*>(&hbuf[0][nd * S_H + quad * 8]);
        const bf16x8 a1 = *reinterpret_cast<const bf16x8*>(&hbuf[0][nd * S_H + 32 + quad * 8]);
        bf16x8 axs;
        if (quad == 0) {
            int node = node0 + nd;
            if (node >= NNODES) node = 0;
            axs = cvt8(x_stat + (size_t)node * STATF);
        } else {
            axs = zero8();
        }
        const f32x4 z4 = {0.f, 0.f, 0.f, 0.f};
        f32x4 aw;
        aw = __builtin_amdgcn_mfma_f32_16x16x32_bf16(a0, Bw0, z4, 0, 0, 0);
        aw = __builtin_amdgcn_mfma_f32_16x16x32_bf16(a1, Bw1, aw, 0, 0, 0);
        aw = __builtin_amdgcn_mfma_f32_16x16x32_bf16(axs, Bw2, aw, 0, 0, 0);
        #pragma unroll
        for (int r = 0; r < 4; ++r) {
            const int node = node0 + mt * 16 + quad * 4 + r;
            if (node < NNODES) t1[(size_t)node * HDIM + jg] = f2bf(aw[r]);
        }
    }
}

// ---------------------------------------------------------------------------
// Layer 1 fused gather+transform, NEW edge layout: lane = (q,f) with
// q = edge slot (0..3), f = feature oct (0..15, 8B each). 4 edges per
// wave-instr pair (vs 2 before): half the VMEM instructions, 2x bytes in
// flight at the same dependence depth. Cross-slot reduce = 2 shfl_xor.
// ---------------------------------------------------------------------------
__global__ __launch_bounds__(256) void gather_transform_kernel(
    const unsigned short* __restrict__ tsrc, const int* __restrict__ cursor,
    const unsigned* __restrict__ csr, const float* __restrict__ b1,
    const float* __restrict__ W2, unsigned short* __restrict__ out)
{
    __shared__ float aggL[16][68];     // stride 68: breaks pow-2 aliasing
    const int tid  = (int)threadIdx.x;
    const int lane = tid & 63;
    const int w    = tid >> 6;         // wave 0..3
    const int q    = lane >> 4;        // edge slot 0..3
    const int f    = lane & 15;        // feature oct: bf16 features 4f..4f+3
    const int col  = lane & 15;
    const int quad = lane >> 4;
    const int node0 = (int)blockIdx.x * 16;
    const int jg = w * 16 + col;

    // preload W2 fragments + bias (latency hides under the gather phase)
    bf16x8 Bw0, Bw1;
    float bk0[8], bk1[8];
    #pragma unroll
    for (int j = 0; j < 8; ++j) {
        Bw0[j] = (short)f2bf(W2[(size_t)(quad * 8 + j) * HDIM + jg]);
        Bw1[j] = (short)f2bf(W2[(size_t)(32 + quad * 8 + j) * HDIM + jg]);
        bk0[j] = b1[quad * 8 + j];
        bk1[j] = b1[32 + quad * 8 + j];
    }

    for (int i = 0; i < 4; ++i) {
        const int nloc = w * 4 + i;
        const int node = node0 + nloc;
        const int beg = node * CAP;
        const int cnt = min(cursor[node], CAP);
        const int end = beg + cnt;
        float a0 = 0.f, a1 = 0.f, a2 = 0.f, a3 = 0.f;
        int p = beg;
        for (; p + 8 <= end; p += 8) {         // 2 groups of 4 edges, ILP 2
            const unsigned e0 = csr[p + q];
            const unsigned e1 = csr[p + 4 + q];
            const u32x2 r0 = *reinterpret_cast<const u32x2*>(
                tsrc + (size_t)(e0 & 0xFFFFu) * HDIM + 4 * f);
            const u32x2 r1 = *reinterpret_cast<const u32x2*>(
                tsrc + (size_t)(e1 & 0xFFFFu) * HDIM + 4 * f);
            const float w0 = __uint_as_float(e0 & 0xFFFF0000u);
            const float w1 = __uint_as_float(e1 & 0xFFFF0000u);
            a0 += w0 * bf2f((unsigned short)(r0[0] & 0xFFFFu));
            a1 += w0 * bf2f((unsigned short)(r0[0] >> 16));
            a2 += w0 * bf2f((unsigned short)(r0[1] & 0xFFFFu));
            a3 += w0 * bf2f((unsigned short)(r0[1] >> 16));
            a0 += w1 * bf2f((unsigned short)(r1[0] & 0xFFFFu));
            a1 += w1 * bf2f((unsigned short)(r1[0] >> 16));
            a2 += w1 * bf2f((unsigned short)(r1[1] & 0xFFFFu));
            a3 += w1 * bf2f((unsigned short)(r1[1] >> 16));
        }
        if (p + 4 <= end) {                    // one group of 4
            const unsigned e0 = csr[p + q];
            const u32x2 r0 = *reinterpret_cast<const u32x2*>(
                tsrc + (size_t)(e0 & 0xFFFFu) * HDIM + 4 * f);
            const float w0 = __uint_as_float(e0 & 0xFFFF0000u);
            a0 += w0 * bf2f((unsigned short)(r0[0] & 0xFFFFu));
            a1 += w0 * bf2f((unsigned short)(r0[0] >> 16));
            a2 += w0 * bf2f((unsigned short)(r0[1] & 0xFFFFu));
            a3 += w0 * bf2f((unsigned short)(r0[1] >> 16));
            p += 4;
        }
        const int rem = end - p;               // 0..3
        if (q < rem) {
            const unsigned e0 = csr[p + q];
            const u32x2 r0 = *reinterpret_cast<const u32x2*>(
                tsrc + (size_t)(e0 & 0xFFFFu) * HDIM + 4 * f);
            const float w0 = __uint_as_float(e0 & 0xFFFF0000u);
            a0 += w0 * bf2f((unsigned short)(r0[0] & 0xFFFFu));
            a1 += w0 * bf2f((unsigned short)(r0[0] >> 16));
            a2 += w0 * bf2f((unsigned short)(r0[1] & 0xFFFFu));
            a3 += w0 * bf2f((unsigned short)(r0[1] >> 16));
        }
        // reduce across the 4 edge slots
        a0 += __shfl_xor(a0, 16, 64); a0 += __shfl_xor(a0, 32, 64);
        a1 += __shfl_xor(a1, 16, 64); a1 += __shfl_xor(a1, 32, 64);
        a2 += __shfl_xor(a2, 16, 64); a2 += __shfl_xor(a2, 32, 64);
        a3 += __shfl_xor(a3, 16, 64); a3 += __shfl_xor(a3, 32, 64);
        if (lane < 16) {                       // q == 0 slot writes
            f32x4 o; o[0] = a0; o[1] = a1; o[2] = a2; o[3] = a3;
            *reinterpret_cast<f32x4*>(&aggL[nloc][4 * f]) = o;
        }
    }
    __syncthreads();

    // ---- transform: t2 = relu(aggL + b1) @ W2 ----
    bf16x8 fa0, fa1;
    #pragma unroll
    for (int j = 0; j < 8; ++j) {
        fa0[j] = (short)f2bf(fmaxf(aggL[col][quad * 8 + j] + bk0[j], 0.f));
        fa1[j] = (short)f2bf(fmaxf(aggL[col][32 + quad * 8 + j] + bk1[j], 0.f));
    }
    const f32x4 z4 = {0.f, 0.f, 0.f, 0.f};
    f32x4 aw;
    aw = __builtin_amdgcn_mfma_f32_16x16x32_bf16(fa0, Bw0, z4, 0, 0, 0);
    aw = __builtin_amdgcn_mfma_f32_16x16x32_bf16(fa1, Bw1, aw, 0, 0, 0);
    #pragma unroll
    for (int r = 0; r < 4; ++r)
        out[(size_t)(node0 + quad * 4 + r) * HDIM + jg] = f2bf(aw[r]);
}

// ---------------------------------------------------------------------------
// Gather + fused head for layer 2, same new 4-edges-per-instr layout.
// ---------------------------------------------------------------------------
__global__ __launch_bounds__(256) void gather_head_kernel(
    const unsigned short* __restrict__ tsrc, const int* __restrict__ cursor,
    const unsigned* __restrict__ csr,
    const float* __restrict__ b2, const float* __restrict__ Wa,
    const float* __restrict__ ba, const float* __restrict__ Wp,
    const float* __restrict__ bp, float* __restrict__ out)
{
    const int node = blockIdx.x * 4 + (threadIdx.x >> 6);
    const int lane = (int)threadIdx.x & 63;
    const int q = lane >> 4;
    const int f = lane & 15;
    if (node >= NNODES) return;
    const int beg = node * CAP;
    const int cnt = min(cursor[node], CAP);
    const int end = beg + cnt;
    float a0 = 0.f, a1 = 0.f, a2 = 0.f, a3 = 0.f;
    int p = beg;
    for (; p + 8 <= end; p += 8) {
        const unsigned e0 = csr[p + q];
        const unsigned e1 = csr[p + 4 + q];
        const u32x2 r0 = *reinterpret_cast<const u32x2*>(
            tsrc + (size_t)(e0 & 0xFFFFu) * HDIM + 4 * f);
        const u32x2 r1 = *reinterpret_cast<const u32x2*>(
            tsrc + (size_t)(e1 & 0xFFFFu) * HDIM + 4 * f);
        const float w0 = __uint_as_float(e0 & 0xFFFF0000u);
        const float w1 = __uint_as_float(e1 & 0xFFFF0000u);
        a0 += w0 * bf2f((unsigned short)(r0[0] & 0xFFFFu));
        a1 += w0 * bf2f((unsigned short)(r0[0] >> 16));
        a2 += w0 * bf2f((unsigned short)(r0[1] & 0xFFFFu));
        a3 += w0 * bf2f((unsigned short)(r0[1] >> 16));
        a0 += w1 * bf2f((unsigned short)(r1[0] & 0xFFFFu));
        a1 += w1 * bf2f((unsigned short)(r1[0] >> 16));
        a2 += w1 * bf2f((unsigned short)(r1[1] & 0xFFFFu));
        a3 += w1 * bf2f((unsigned short)(r1[1] >> 16));
    }
    if (p + 4 <= end) {
        const unsigned e0 = csr[p + q];
        const u32x2 r0 = *reinterpret_cast<const u32x2*>(
            tsrc + (size_t)(e0 & 0xFFFFu) * HDIM + 4 * f);
        const float w0 = __uint_as_float(e0 & 0xFFFF0000u);
        a0 += w0 * bf2f((unsigned short)(r0[0] & 0xFFFFu));
        a1 += w0 * bf2f((unsigned short)(r0[0] >> 16));
        a2 += w0 * bf2f((unsigned short)(r0[1] & 0xFFFFu));
        a3 += w0 * bf2f((unsigned short)(r0[1] >> 16));
        p += 4;
    }
    const int rem = end - p;
    if (q < rem) {
        const unsigned e0 = csr[p + q];
        const u32x2 r0 = *reinterpret_cast<const u32x2*>(
            tsrc + (size_t)(e0 & 0xFFFFu) * HDIM + 4 * f);
        const float w0 = __uint_as_float(e0 & 0xFFFF0000u);
        a0 += w0 * bf2f((unsigned short)(r0[0] & 0xFFFFu));
        a1 += w0 * bf2f((unsigned short)(r0[0] >> 16));
        a2 += w0 * bf2f((unsigned short)(r0[1] & 0xFFFFu));
        a3 += w0 * bf2f((unsigned short)(r0[1] >> 16));
    }
    a0 += __shfl_xor(a0, 16, 64); a0 += __shfl_xor(a0, 32, 64);
    a1 += __shfl_xor(a1, 16, 64); a1 += __shfl_xor(a1, 32, 64);
    a2 += __shfl_xor(a2, 16, 64); a2 += __shfl_xor(a2, 32, 64);
    a3 += __shfl_xor(a3, 16, 64); a3 += __shfl_xor(a3, 32, 64);

    // head: every lane owns features 4f..4f+3 (q slots are duplicates)
    const f32x4 bb = *reinterpret_cast<const f32x4*>(b2 + 4 * f);
    const f32x4 wa = *reinterpret_cast<const f32x4*>(Wa + 4 * f);
    const f32x4 wp = *reinterpret_cast<const f32x4*>(Wp + 4 * f);
    const float h0 = fmaxf(a0 + bb[0], 0.f);
    const float h1 = fmaxf(a1 + bb[1], 0.f);
    const float h2 = fmaxf(a2 + bb[2], 0.f);
    const float h3 = fmaxf(a3 + bb[3], 0.f);
    float sa = h0 * wa[0] + h1 * wa[1] + h2 * wa[2] + h3 * wa[3];
    float sp = h0 * wp[0] + h1 * wp[1] + h2 * wp[2] + h3 * wp[3];
    #pragma unroll
    for (int off = 1; off < 16; off <<= 1) {
        sa += __shfl_xor(sa, off, 64);
        sp += __shfl_xor(sp, off, 64);
    }
    if (lane == 0) {
        out[node] = sa + ba[0];
        out[NNODES + node] = sp + bp[0];
    }
}

extern "C" void kernel_launch(void* const* d_in, const int* in_sizes, int n_in,
                              void* d_out, int out_size, void* d_ws, size_t ws_size,
                              hipStream_t stream)
{
    const float* x_dyn  = (const float*)d_in[0];
    const float* x_stat = (const float*)d_in[1];
    const int*   eidx   = (const int*)  d_in[2];
    const float* ew     = (const float*)d_in[3];
    const float* Wih    = (const float*)d_in[4];
    const float* Whh    = (const float*)d_in[5];
    const float* bih    = (const float*)d_in[6];
    const float* bhh    = (const float*)d_in[7];
    const float* W1     = (const float*)d_in[8];
    const float* b1     = (const float*)d_in[9];
    const float* W2     = (const float*)d_in[10];
    const float* b2     = (const float*)d_in[11];
    const float* Wa     = (const float*)d_in[12];
    const float* ba     = (const float*)d_in[13];
    const float* Wp     = (const float*)d_in[14];
    const float* bp     = (const float*)d_in[15];

    const int* srcv = eidx;
    const int* dstv = eidx + NEDGES;

    // workspace layout (4B units)
    const size_t NH = (size_t)NNODES * HDIM;    // 3.2M elements
    float* ws   = (float*)d_ws;
    unsigned short* t1 = (unsigned short*)ws;                 // [NH] bf16
    unsigned short* t2 = (unsigned short*)(ws + NH / 2);      // [NH] bf16
    unsigned* csr = (unsigned*)(ws + NH);             // [NNODES*CAP] packed
    int* cursor = (int*)(csr + (size_t)NNODES * CAP); // [NNODES]

    dim3 blk(256);

    // cursor must be zero before the combined launch
    hipMemsetAsync(cursor, 0, (size_t)NNODES * sizeof(int), stream);

    // ---- GRU + W1 co-scheduled with bucket-CSR fill ----
    gru_fill_kernel<<<dim3(GRU_BLOCKS + FILL_CHUNKS * 8), blk, 0, stream>>>(
        x_dyn, x_stat, Wih, Whh, bih, bhh, W1, t1,
        srcv, dstv, ew, cursor, csr);

    // ---- layer 1 (transform fused into gather) ----
    gather_transform_kernel<<<dim3(NNODES / 16), blk, 0, stream>>>(
        t1, cursor, csr, b1, W2, t2);

    // ---- layer 2 (head fused into gather) ----
    gather_head_kernel<<<dim3((NNODES + 3) / 4), blk, 0, stream>>>(
        t2, cursor, csr, b2, Wa, ba, Wp, bp, (float*)d_out);
}